// Round 4
// baseline (178.277 us; speedup 1.0000x reference)
//
#include <hip/hip_runtime.h>
#include <math.h>

// Problem constants
#define TT 16384   // tokens
#define HH 2048    // hidden
#define EE 64      // experts
#define KK 8       // top_k

#define TB 32          // tokens per block
#define HC 64          // h per chunk
#define NCH (HH / HC)  // 32 chunks

// Output layout (flat float32):
// probs [TT][KK] | indices [TT][KK] | map [TT][EE] | aux scalar
#define IDX_OFF ((size_t)TT * KK)
#define MAP_OFF ((size_t)2 * TT * KK)
#define AUX_OFF ((size_t)2 * TT * KK + (size_t)TT * EE)

// Shared memory (doubles). Two overlapping uses:
//  - staging: stH [16][33] float4 (8448 B) | stW [16][65] float4 (16640 B)
//  - reduction/epilogue: redA, redB each [32][66] f64 (16896 B)
#define REDSTRIDE 66
#define REDSZ (TB * REDSTRIDE)        // 2112 doubles
#define SMEM_DOUBLES (2 * REDSZ)      // 4224 doubles = 33792 B (>= staging 25088 B)

__global__ __launch_bounds__(256, 2)
void router_kernel(const float* __restrict__ hidden,
                   const float* __restrict__ gate_w,
                   const float* __restrict__ bias,
                   float* __restrict__ out)
{
    __shared__ double smem[SMEM_DOUBLES];

    float4* stBase = reinterpret_cast<float4*>(smem);
    float4* stH = stBase;          // [16][33]
    float4* stW = stBase + 528;    // [16][65]
    const float2* pH2 = reinterpret_cast<const float2*>(stH);
    const float2* pW2 = reinterpret_cast<const float2*>(stW);
    double* redA = smem;
    double* redB = smem + REDSZ;

    const int tid = threadIdx.x;
    const int s   = tid >> 5;          // h-split 0..7 (half-wave granular)
    const int tg  = (tid >> 3) & 3;    // tokens tg + 4i, i=0..7
    const int eg  = tid & 7;           // experts eg + 8j, j=0..7
    const int tok0 = blockIdx.x * TB;

    // staging coords: thread stages H f4-slots (f4, tw), (f4, tw+16); W (f4, tw+16k)
    const int f4 = tid & 15;
    const int tw = tid >> 4;           // 0..15

    const float* hbase = hidden + (size_t)(tok0 + tw) * HH + 4 * f4;
    const float* wbase = gate_w + (size_t)tw * HH + 4 * f4;

    // LDS read bases (float2 element units)
    const int baseH = 132 * s + 2 * tg;   // + 66*up + 8*i + p
    const int baseW = 260 * s + 2 * eg;   // + 130*up + 16*j + p

    double acc[8][8];
    #pragma unroll
    for (int i = 0; i < 8; ++i)
        #pragma unroll
        for (int j = 0; j < 8; ++j) acc[i][j] = 0.0;

    // prologue: load chunk 0
    float4 hv[2], wv[4];
    #pragma unroll
    for (int k = 0; k < 2; ++k)
        hv[k] = *reinterpret_cast<const float4*>(hbase + (size_t)16 * k * HH);
    #pragma unroll
    for (int k = 0; k < 4; ++k)
        wv[k] = *reinterpret_cast<const float4*>(wbase + (size_t)16 * k * HH);

    for (int c = 0; c < NCH; ++c) {
        __syncthreads();   // previous chunk's compute done
        // stage (R3's conflict-clean pattern)
        stH[f4 * 33 + tw]      = hv[0];
        stH[f4 * 33 + tw + 16] = hv[1];
        #pragma unroll
        for (int k = 0; k < 4; ++k)
            stW[f4 * 65 + tw + 16 * k] = wv[k];
        __syncthreads();   // staging visible

        // prefetch next chunk (lands during compute)
        if (c + 1 < NCH) {
            #pragma unroll
            for (int k = 0; k < 2; ++k)
                hv[k] = *reinterpret_cast<const float4*>(
                    hbase + (size_t)16 * k * HH + (c + 1) * HC);
            #pragma unroll
            for (int k = 0; k < 4; ++k)
                wv[k] = *reinterpret_cast<const float4*>(
                    wbase + (size_t)16 * k * HH + (c + 1) * HC);
        }

        // compute: split s handles h in [8s, 8s+8): 2 f4-slots x 2 pairs
        #pragma unroll
        for (int up = 0; up < 2; ++up) {
            #pragma unroll
            for (int p = 0; p < 2; ++p) {
                float2 ha[8], wb[8];
                #pragma unroll
                for (int i = 0; i < 8; ++i)
                    ha[i] = pH2[baseH + 66 * up + 8 * i + p];
                #pragma unroll
                for (int j = 0; j < 8; ++j)
                    wb[j] = pW2[baseW + 130 * up + 16 * j + p];

                #pragma unroll
                for (int cc = 0; cc < 2; ++cc) {
                    double hd[8], wd[8];
                    #pragma unroll
                    for (int i = 0; i < 8; ++i)
                        hd[i] = (double)(cc ? ha[i].y : ha[i].x);
                    #pragma unroll
                    for (int j = 0; j < 8; ++j)
                        wd[j] = (double)(cc ? wb[j].y : wb[j].x);
                    #pragma unroll
                    for (int i = 0; i < 8; ++i)
                        #pragma unroll
                        for (int j = 0; j < 8; ++j)
                            acc[i][j] = fma(hd[i], wd[j], acc[i][j]);
                }
            }
        }
    }
    __syncthreads();   // compute done; staging area now dead

    // ---- reduce 8 split-partials: 4-round tree via redA/redB ----
    // layout: red[tok][eg][j] (+2 pad/row): expert e=eg+8j at [t*66 + (e&7)*8 + (e>>3)]
    auto writeRed = [&](double* buf) {
        #pragma unroll
        for (int i = 0; i < 8; ++i) {
            double* row = buf + (size_t)(tg + 4 * i) * REDSTRIDE + eg * 8;
            #pragma unroll
            for (int jp = 0; jp < 4; ++jp)
                *reinterpret_cast<double2*>(row + 2 * jp) =
                    make_double2(acc[i][2 * jp], acc[i][2 * jp + 1]);
        }
    };
    auto addRed = [&](const double* buf) {
        #pragma unroll
        for (int i = 0; i < 8; ++i) {
            const double* row = buf + (size_t)(tg + 4 * i) * REDSTRIDE + eg * 8;
            #pragma unroll
            for (int jp = 0; jp < 4; ++jp) {
                double2 v = *reinterpret_cast<const double2*>(row + 2 * jp);
                acc[i][2 * jp]     += v.x;
                acc[i][2 * jp + 1] += v.y;
            }
        }
    };

    if (s == 4) writeRed(redA);
    if (s == 5) writeRed(redB);
    __syncthreads();
    if (s == 0) addRed(redA);
    if (s == 1) addRed(redB);
    __syncthreads();
    if (s == 6) writeRed(redA);
    if (s == 7) writeRed(redB);
    __syncthreads();
    if (s == 2) addRed(redA);
    if (s == 3) addRed(redB);
    __syncthreads();
    if (s == 2) writeRed(redA);
    if (s == 3) writeRed(redB);
    __syncthreads();
    if (s == 0) addRed(redA);
    if (s == 1) addRed(redB);
    __syncthreads();
    if (s == 1) writeRed(redA);
    __syncthreads();
    if (s == 0) { addRed(redA); writeRed(redB); }
    __syncthreads();

    // ---- epilogue: 8 lanes per token, all 256 threads ----
    const int t = tid >> 3;   // 0..31
    const int q = tid & 7;    // lane owns experts q + 8i, i=0..7
    const int tok = tok0 + t;

    double lv[8];
    #pragma unroll
    for (int jp = 0; jp < 4; ++jp) {
        double2 v = *reinterpret_cast<const double2*>(
            redB + (size_t)t * REDSTRIDE + q * 8 + 2 * jp);
        lv[2 * jp] = v.x; lv[2 * jp + 1] = v.y;
    }

    // row max
    double mx = lv[0];
    #pragma unroll
    for (int i = 1; i < 8; ++i) mx = fmax(mx, lv[i]);
    #pragma unroll
    for (int sh = 1; sh < 8; sh <<= 1) mx = fmax(mx, __shfl_xor(mx, sh, 64));

    // exp + denom
    double ex[8], psum = 0.0;
    #pragma unroll
    for (int i = 0; i < 8; ++i) { ex[i] = exp(lv[i] - mx); psum += ex[i]; }
    #pragma unroll
    for (int sh = 1; sh < 8; sh <<= 1) psum += __shfl_xor(psum, sh, 64);
    const double inv = 1.0 / psum;

    double pr[8], selv[8];
    #pragma unroll
    for (int i = 0; i < 8; ++i) {
        pr[i]   = ex[i] * inv;
        selv[i] = pr[i] + (double)bias[q + 8 * i];
    }

    // top-8: lane-local argmax over 8, then 3-step shfl reduce (8 lanes/token)
    unsigned long long mk = 0ull;
    double myprob = 0.0;
    int myidx = 0;
    #pragma unroll
    for (int k = 0; k < KK; ++k) {
        double bs = selv[0], bp = pr[0];
        int bi = q;
        #pragma unroll
        for (int i = 1; i < 8; ++i) {
            if (selv[i] > bs) { bs = selv[i]; bp = pr[i]; bi = q + 8 * i; }
        }
        #pragma unroll
        for (int sh = 1; sh < 8; sh <<= 1) {
            double os = __shfl_xor(bs, sh, 64);
            double op = __shfl_xor(bp, sh, 64);
            int    oi = __shfl_xor(bi, sh, 64);
            if (os > bs || (os == bs && oi < bi)) { bs = os; bp = op; bi = oi; }
        }
        if (q == k) { myprob = bp; myidx = bi; }
        mk |= (1ull << bi);
        if ((bi & 7) == q) selv[bi >> 3] = -INFINITY;
    }

    // renormalize over the 8 winners (each lane holds exactly one)
    double ps = myprob;
    #pragma unroll
    for (int sh = 1; sh < 8; sh <<= 1) ps += __shfl_xor(ps, sh, 64);
    const double rinv = 1.0 / (ps + 1e-9);

    out[(size_t)tok * KK + q]           = (float)(myprob * rinv);
    out[IDX_OFF + (size_t)tok * KK + q] = (float)myidx;

    // routing map: lane q writes experts 8q..8q+7 as two float4
    {
        float4 a, b;
        a.x = ((mk >> (8 * q + 0)) & 1ull) ? 1.0f : 0.0f;
        a.y = ((mk >> (8 * q + 1)) & 1ull) ? 1.0f : 0.0f;
        a.z = ((mk >> (8 * q + 2)) & 1ull) ? 1.0f : 0.0f;
        a.w = ((mk >> (8 * q + 3)) & 1ull) ? 1.0f : 0.0f;
        b.x = ((mk >> (8 * q + 4)) & 1ull) ? 1.0f : 0.0f;
        b.y = ((mk >> (8 * q + 5)) & 1ull) ? 1.0f : 0.0f;
        b.z = ((mk >> (8 * q + 6)) & 1ull) ? 1.0f : 0.0f;
        b.w = ((mk >> (8 * q + 7)) & 1ull) ? 1.0f : 0.0f;
        float* mo = out + MAP_OFF + (size_t)tok * EE + 8 * q;
        reinterpret_cast<float4*>(mo)[0] = a;
        reinterpret_cast<float4*>(mo)[1] = b;
    }

    if (blockIdx.x == 0 && tid == 0) out[AUX_OFF] = 0.0f;
}

extern "C" void kernel_launch(void* const* d_in, const int* in_sizes, int n_in,
                              void* d_out, int out_size, void* d_ws, size_t ws_size,
                              hipStream_t stream) {
    const float* hidden = (const float*)d_in[0];  // [16384, 2048] f32
    const float* gate_w = (const float*)d_in[1];  // [64, 2048] f32
    const float* bias   = (const float*)d_in[2];  // [64] f32
    float* out = (float*)d_out;

    router_kernel<<<TT / TB, 256, 0, stream>>>(hidden, gate_w, bias, out);
}